// Round 1
// baseline (545.055 us; speedup 1.0000x reference)
//
#include <hip/hip_runtime.h>
#include <hip/hip_bf16.h>

// GCN 2-layer + global_add_pool on MI355X.
// Pipeline:
//  1. memset cnt
//  2. deg_count: atomic in-degree histogram over dst
//  3. block_sums / scan_bsum / scan_final: exclusive scan -> CSR row_start,
//     cursor copy, dinv = rsqrt(deg+1)
//  4. fill_edges: CSR fill (src_sorted, enorm = dinv[s]*dinv[d])
//  5. gemm_xw: h = x @ W1              (f32 tiled, 128x128 block tile)
//  6. agg<true>:  o = relu(gather + dinv^2*h + b1)   (gather-based, no atomics)
//  7. gemm_xw: h = o @ W2
//  8. agg<false>: o = gather + dinv^2*h + b2
//  9. pool: block-per-graph segment sum (batch sorted), writes d_out fully

__global__ void deg_count(const int* __restrict__ ei, int* __restrict__ cnt, int E) {
    int e = blockIdx.x * 256 + threadIdx.x;
    if (e < E) atomicAdd(&cnt[ei[E + e]], 1);  // ei[1][e] = dst
}

__global__ void block_sums(const int* __restrict__ cnt, int* __restrict__ bsum, int n) {
    __shared__ int s[256];
    int base = blockIdx.x * 1024;
    int t = threadIdx.x;
    int v = 0;
#pragma unroll
    for (int i = 0; i < 4; i++) {
        int idx = base + t * 4 + i;
        if (idx < n) v += cnt[idx];
    }
    s[t] = v;
    __syncthreads();
    for (int off = 128; off > 0; off >>= 1) {
        if (t < off) s[t] += s[t + off];
        __syncthreads();
    }
    if (t == 0) bsum[blockIdx.x] = s[0];
}

__global__ void scan_bsum(int* __restrict__ bsum, int nb) {
    if (threadIdx.x == 0 && blockIdx.x == 0) {
        int run = 0;
        for (int i = 0; i < nb; i++) { int v = bsum[i]; bsum[i] = run; run += v; }
    }
}

__global__ void scan_final(const int* __restrict__ cnt, const int* __restrict__ bsum,
                           int* __restrict__ row_start, int* __restrict__ cursor,
                           float* __restrict__ dinv, int n) {
    __shared__ int s[256];
    int base = blockIdx.x * 1024;
    int t = threadIdx.x;
    int loc[4];
    int v = 0;
#pragma unroll
    for (int i = 0; i < 4; i++) {
        int idx = base + t * 4 + i;
        loc[i] = (idx < n) ? cnt[idx] : 0;
        v += loc[i];
    }
    s[t] = v;
    __syncthreads();
    for (int off = 1; off < 256; off *= 2) {
        int u = (t >= off) ? s[t - off] : 0;
        __syncthreads();
        s[t] += u;
        __syncthreads();
    }
    int excl = s[t] - v + bsum[blockIdx.x];
#pragma unroll
    for (int i = 0; i < 4; i++) {
        int idx = base + t * 4 + i;
        if (idx < n) {
            row_start[idx] = excl;
            cursor[idx] = excl;
            dinv[idx] = rsqrtf((float)loc[i] + 1.0f);
            excl += loc[i];
        }
    }
}

__global__ void fill_edges(const int* __restrict__ ei, int* __restrict__ cursor,
                           const float* __restrict__ dinv, int* __restrict__ src_sorted,
                           float* __restrict__ enorm, int E) {
    int e = blockIdx.x * 256 + threadIdx.x;
    if (e >= E) return;
    int s = ei[e];
    int d = ei[E + e];
    int pos = atomicAdd(&cursor[d], 1);
    src_sorted[pos] = s;
    enorm[pos] = dinv[s] * dinv[d];
}

// C[M x 128] = A[M x 128] @ W[128 x 128], f32. Block tile 128 rows, full N=K=128.
__global__ __launch_bounds__(256) void gemm_xw(const float* __restrict__ A,
                                               const float* __restrict__ W,
                                               float* __restrict__ C, int M) {
    __shared__ float As[16][132];  // [k][row], 132*4B = 33*16B: float4-aligned rows, conflict-free
    __shared__ float Bs[16][128];  // [k][col]
    int t = threadIdx.x;
    int tx = t & 15;   // col group: cols tx + j*16
    int ty = t >> 4;   // row group: rows ty*8 + i
    int row0 = blockIdx.x * 128;
    float acc[8][8];
#pragma unroll
    for (int i = 0; i < 8; i++)
#pragma unroll
        for (int j = 0; j < 8; j++) acc[i][j] = 0.f;

    for (int k0 = 0; k0 < 128; k0 += 16) {
        // stage A tile (transposed into As[k][row])
#pragma unroll
        for (int i = 0; i < 2; i++) {
            int idx = t + i * 256;
            int r = idx >> 2;
            int c4 = idx & 3;
            int grow = row0 + r;
            float4 v = make_float4(0.f, 0.f, 0.f, 0.f);
            if (grow < M) v = ((const float4*)A)[(size_t)grow * 32 + (k0 >> 2) + c4];
            As[c4 * 4 + 0][r] = v.x;
            As[c4 * 4 + 1][r] = v.y;
            As[c4 * 4 + 2][r] = v.z;
            As[c4 * 4 + 3][r] = v.w;
        }
        // stage B tile
#pragma unroll
        for (int i = 0; i < 2; i++) {
            int idx = t + i * 256;
            int r = idx >> 5;
            int c4 = idx & 31;
            *((float4*)&Bs[r][c4 * 4]) = ((const float4*)W)[(size_t)(k0 + r) * 32 + c4];
        }
        __syncthreads();
#pragma unroll
        for (int k = 0; k < 16; k++) {
            float a[8], b[8];
            float4 a0 = *((const float4*)&As[k][ty * 8]);
            float4 a1 = *((const float4*)&As[k][ty * 8 + 4]);
            a[0] = a0.x; a[1] = a0.y; a[2] = a0.z; a[3] = a0.w;
            a[4] = a1.x; a[5] = a1.y; a[6] = a1.z; a[7] = a1.w;
#pragma unroll
            for (int j = 0; j < 8; j++) b[j] = Bs[k][tx + j * 16];
#pragma unroll
            for (int i = 0; i < 8; i++)
#pragma unroll
                for (int j = 0; j < 8; j++) acc[i][j] = fmaf(a[i], b[j], acc[i][j]);
        }
        __syncthreads();
    }
#pragma unroll
    for (int i = 0; i < 8; i++) {
        int row = row0 + ty * 8 + i;
        if (row < M) {
#pragma unroll
            for (int j = 0; j < 8; j++) C[(size_t)row * 128 + tx + j * 16] = acc[i][j];
        }
    }
}

// Gather-based GCN aggregation: one wave per node, lane handles 2 features.
template <bool RELU>
__global__ __launch_bounds__(256) void agg(const float* __restrict__ h,
                                           const int* __restrict__ src_sorted,
                                           const float* __restrict__ enorm,
                                           const int* __restrict__ row_start,
                                           const int* __restrict__ cnt,
                                           const float* __restrict__ dinv,
                                           const float* __restrict__ bias,
                                           float* __restrict__ out, int n) {
    int node = blockIdx.x * 4 + (threadIdx.x >> 6);
    if (node >= n) return;
    int lane = threadIdx.x & 63;
    int s0 = row_start[node];
    int c = cnt[node];
    const float2* h2 = (const float2*)h;
    float ax = 0.f, ay = 0.f;
    for (int e = 0; e < c; e++) {
        int s = src_sorted[s0 + e];
        float w = enorm[s0 + e];
        float2 hv = h2[(size_t)s * 64 + lane];
        ax = fmaf(w, hv.x, ax);
        ay = fmaf(w, hv.y, ay);
    }
    float di = dinv[node];
    float sw = di * di;
    float2 hs = h2[(size_t)node * 64 + lane];
    float2 bv = ((const float2*)bias)[lane];
    float ox = ax + sw * hs.x + bv.x;
    float oy = ay + sw * hs.y + bv.y;
    if (RELU) { ox = fmaxf(ox, 0.f); oy = fmaxf(oy, 0.f); }
    ((float2*)out)[(size_t)node * 64 + lane] = make_float2(ox, oy);
}

// global_add_pool: one block per graph (batch sorted), binary-search boundaries.
__global__ __launch_bounds__(128) void pool(const float* __restrict__ feat,
                                            const int* __restrict__ batch,
                                            float* __restrict__ out, int n) {
    int g = blockIdx.x;
    int f = threadIdx.x;
    int lo = 0, hi = n;
    while (lo < hi) { int mid = (lo + hi) >> 1; if (batch[mid] < g) lo = mid + 1; else hi = mid; }
    int start = lo;
    hi = n;
    while (lo < hi) { int mid = (lo + hi) >> 1; if (batch[mid] < g + 1) lo = mid + 1; else hi = mid; }
    int end = lo;
    float acc = 0.f;
    for (int i = start; i < end; i++) acc += feat[(size_t)i * 128 + f];
    out[g * 128 + f] = acc;
}

extern "C" void kernel_launch(void* const* d_in, const int* in_sizes, int n_in,
                              void* d_out, int out_size, void* d_ws, size_t ws_size,
                              hipStream_t stream) {
    const float* x  = (const float*)d_in[0];
    const int*   ei = (const int*)d_in[1];
    const int*   batch = (const int*)d_in[2];
    const float* W1 = (const float*)d_in[3];
    const float* b1 = (const float*)d_in[4];
    const float* W2 = (const float*)d_in[5];
    const float* b2 = (const float*)d_in[6];
    float* out = (float*)d_out;

    const int N = in_sizes[2];       // 50000
    const int E = in_sizes[1] / 2;   // 800000

    // workspace layout
    float* h  = (float*)d_ws;                       // N*128
    float* o  = h + (size_t)N * 128;                // N*128
    int* cnt  = (int*)(o + (size_t)N * 128);        // N
    int* row_start = cnt + N;                       // N
    int* cursor    = row_start + N;                 // N
    float* dinv    = (float*)(cursor + N);          // N
    int* src_sorted = (int*)(dinv + N);             // E
    float* enorm    = (float*)(src_sorted + E);     // E
    int* bsum       = (int*)(enorm + E);            // small

    const int nb = (N + 1023) / 1024;

    hipMemsetAsync(cnt, 0, (size_t)N * sizeof(int), stream);
    deg_count<<<(E + 255) / 256, 256, 0, stream>>>(ei, cnt, E);
    block_sums<<<nb, 256, 0, stream>>>(cnt, bsum, N);
    scan_bsum<<<1, 64, 0, stream>>>(bsum, nb);
    scan_final<<<nb, 256, 0, stream>>>(cnt, bsum, row_start, cursor, dinv, N);
    fill_edges<<<(E + 255) / 256, 256, 0, stream>>>(ei, cursor, dinv, src_sorted, enorm, E);

    const int gemm_grid = (N + 127) / 128;
    const int agg_grid = (N + 3) / 4;

    // layer 1
    gemm_xw<<<gemm_grid, 256, 0, stream>>>(x, W1, h, N);
    agg<true><<<agg_grid, 256, 0, stream>>>(h, src_sorted, enorm, row_start, cnt, dinv, b1, o, N);
    // layer 2
    gemm_xw<<<gemm_grid, 256, 0, stream>>>(o, W2, h, N);
    agg<false><<<agg_grid, 256, 0, stream>>>(h, src_sorted, enorm, row_start, cnt, dinv, b2, o, N);
    // pool
    pool<<<128, 128, 0, stream>>>(o, batch, out, N);
}

// Round 2
// 391.183 us; speedup vs baseline: 1.3934x; 1.3934x over previous
//
#include <hip/hip_runtime.h>
#include <hip/hip_bf16.h>

// GCN 2-layer + global_add_pool on MI355X.
// R1 changes:
//  - pool: was 1 block/graph (256 waves total, 116us latency-bound) -> now
//    chunked over nodes, 4 waves/block, register accumulate + atomic flush
//    on graph boundary (batch sorted => ~2 flushes/wave). d_out zero-init'd.
//  - agg: edge loop unrolled x4 to put 4 independent (idx -> feature-row)
//    load chains in flight.

__global__ void deg_count(const int* __restrict__ ei, int* __restrict__ cnt, int E) {
    int e = blockIdx.x * 256 + threadIdx.x;
    if (e < E) atomicAdd(&cnt[ei[E + e]], 1);  // ei[1][e] = dst
}

__global__ void block_sums(const int* __restrict__ cnt, int* __restrict__ bsum, int n) {
    __shared__ int s[256];
    int base = blockIdx.x * 1024;
    int t = threadIdx.x;
    int v = 0;
#pragma unroll
    for (int i = 0; i < 4; i++) {
        int idx = base + t * 4 + i;
        if (idx < n) v += cnt[idx];
    }
    s[t] = v;
    __syncthreads();
    for (int off = 128; off > 0; off >>= 1) {
        if (t < off) s[t] += s[t + off];
        __syncthreads();
    }
    if (t == 0) bsum[blockIdx.x] = s[0];
}

__global__ void scan_bsum(int* __restrict__ bsum, int nb) {
    if (threadIdx.x == 0 && blockIdx.x == 0) {
        int run = 0;
        for (int i = 0; i < nb; i++) { int v = bsum[i]; bsum[i] = run; run += v; }
    }
}

__global__ void scan_final(const int* __restrict__ cnt, const int* __restrict__ bsum,
                           int* __restrict__ row_start, int* __restrict__ cursor,
                           float* __restrict__ dinv, int n) {
    __shared__ int s[256];
    int base = blockIdx.x * 1024;
    int t = threadIdx.x;
    int loc[4];
    int v = 0;
#pragma unroll
    for (int i = 0; i < 4; i++) {
        int idx = base + t * 4 + i;
        loc[i] = (idx < n) ? cnt[idx] : 0;
        v += loc[i];
    }
    s[t] = v;
    __syncthreads();
    for (int off = 1; off < 256; off *= 2) {
        int u = (t >= off) ? s[t - off] : 0;
        __syncthreads();
        s[t] += u;
        __syncthreads();
    }
    int excl = s[t] - v + bsum[blockIdx.x];
#pragma unroll
    for (int i = 0; i < 4; i++) {
        int idx = base + t * 4 + i;
        if (idx < n) {
            row_start[idx] = excl;
            cursor[idx] = excl;
            dinv[idx] = rsqrtf((float)loc[i] + 1.0f);
            excl += loc[i];
        }
    }
}

__global__ void fill_edges(const int* __restrict__ ei, int* __restrict__ cursor,
                           const float* __restrict__ dinv, int* __restrict__ src_sorted,
                           float* __restrict__ enorm, int E) {
    int e = blockIdx.x * 256 + threadIdx.x;
    if (e >= E) return;
    int s = ei[e];
    int d = ei[E + e];
    int pos = atomicAdd(&cursor[d], 1);
    src_sorted[pos] = s;
    enorm[pos] = dinv[s] * dinv[d];
}

// C[M x 128] = A[M x 128] @ W[128 x 128], f32. Block tile 128 rows, full N=K=128.
__global__ __launch_bounds__(256) void gemm_xw(const float* __restrict__ A,
                                               const float* __restrict__ W,
                                               float* __restrict__ C, int M) {
    __shared__ float As[16][132];
    __shared__ float Bs[16][128];
    int t = threadIdx.x;
    int tx = t & 15;
    int ty = t >> 4;
    int row0 = blockIdx.x * 128;
    float acc[8][8];
#pragma unroll
    for (int i = 0; i < 8; i++)
#pragma unroll
        for (int j = 0; j < 8; j++) acc[i][j] = 0.f;

    for (int k0 = 0; k0 < 128; k0 += 16) {
#pragma unroll
        for (int i = 0; i < 2; i++) {
            int idx = t + i * 256;
            int r = idx >> 2;
            int c4 = idx & 3;
            int grow = row0 + r;
            float4 v = make_float4(0.f, 0.f, 0.f, 0.f);
            if (grow < M) v = ((const float4*)A)[(size_t)grow * 32 + (k0 >> 2) + c4];
            As[c4 * 4 + 0][r] = v.x;
            As[c4 * 4 + 1][r] = v.y;
            As[c4 * 4 + 2][r] = v.z;
            As[c4 * 4 + 3][r] = v.w;
        }
#pragma unroll
        for (int i = 0; i < 2; i++) {
            int idx = t + i * 256;
            int r = idx >> 5;
            int c4 = idx & 31;
            *((float4*)&Bs[r][c4 * 4]) = ((const float4*)W)[(size_t)(k0 + r) * 32 + c4];
        }
        __syncthreads();
#pragma unroll
        for (int k = 0; k < 16; k++) {
            float a[8], b[8];
            float4 a0 = *((const float4*)&As[k][ty * 8]);
            float4 a1 = *((const float4*)&As[k][ty * 8 + 4]);
            a[0] = a0.x; a[1] = a0.y; a[2] = a0.z; a[3] = a0.w;
            a[4] = a1.x; a[5] = a1.y; a[6] = a1.z; a[7] = a1.w;
#pragma unroll
            for (int j = 0; j < 8; j++) b[j] = Bs[k][tx + j * 16];
#pragma unroll
            for (int i = 0; i < 8; i++)
#pragma unroll
                for (int j = 0; j < 8; j++) acc[i][j] = fmaf(a[i], b[j], acc[i][j]);
        }
        __syncthreads();
    }
#pragma unroll
    for (int i = 0; i < 8; i++) {
        int row = row0 + ty * 8 + i;
        if (row < M) {
#pragma unroll
            for (int j = 0; j < 8; j++) C[(size_t)row * 128 + tx + j * 16] = acc[i][j];
        }
    }
}

// Gather-based GCN aggregation: one wave per node, lane handles 2 features.
// Edge loop unrolled x4: 4 independent (index->feature-row) load chains in flight.
template <bool RELU>
__global__ __launch_bounds__(256) void agg(const float* __restrict__ h,
                                           const int* __restrict__ src_sorted,
                                           const float* __restrict__ enorm,
                                           const int* __restrict__ row_start,
                                           const int* __restrict__ cnt,
                                           const float* __restrict__ dinv,
                                           const float* __restrict__ bias,
                                           float* __restrict__ out, int n) {
    int node = blockIdx.x * 4 + (threadIdx.x >> 6);
    if (node >= n) return;
    int lane = threadIdx.x & 63;
    int s0 = row_start[node];
    int c = cnt[node];
    const float2* h2 = (const float2*)h;
    float ax = 0.f, ay = 0.f;
    float bx = 0.f, by = 0.f;
    int e = 0;
    for (; e + 4 <= c; e += 4) {
        int sA = src_sorted[s0 + e + 0];
        int sB = src_sorted[s0 + e + 1];
        int sC = src_sorted[s0 + e + 2];
        int sD = src_sorted[s0 + e + 3];
        float wA = enorm[s0 + e + 0];
        float wB = enorm[s0 + e + 1];
        float wC = enorm[s0 + e + 2];
        float wD = enorm[s0 + e + 3];
        float2 vA = h2[(size_t)sA * 64 + lane];
        float2 vB = h2[(size_t)sB * 64 + lane];
        float2 vC = h2[(size_t)sC * 64 + lane];
        float2 vD = h2[(size_t)sD * 64 + lane];
        ax = fmaf(wA, vA.x, ax); ay = fmaf(wA, vA.y, ay);
        bx = fmaf(wB, vB.x, bx); by = fmaf(wB, vB.y, by);
        ax = fmaf(wC, vC.x, ax); ay = fmaf(wC, vC.y, ay);
        bx = fmaf(wD, vD.x, bx); by = fmaf(wD, vD.y, by);
    }
    for (; e < c; e++) {
        int s = src_sorted[s0 + e];
        float w = enorm[s0 + e];
        float2 hv = h2[(size_t)s * 64 + lane];
        ax = fmaf(w, hv.x, ax);
        ay = fmaf(w, hv.y, ay);
    }
    ax += bx; ay += by;
    float di = dinv[node];
    float sw = di * di;
    float2 hs = h2[(size_t)node * 64 + lane];
    float2 bv = ((const float2*)bias)[lane];
    float ox = ax + sw * hs.x + bv.x;
    float oy = ay + sw * hs.y + bv.y;
    if (RELU) { ox = fmaxf(ox, 0.f); oy = fmaxf(oy, 0.f); }
    ((float2*)out)[(size_t)node * 64 + lane] = make_float2(ox, oy);
}

// global_add_pool v2: chunk of POOL_CHUNK nodes per block, 4 waves/block,
// lane holds float2 (64 lanes x 2 = 128 features). Register accumulate,
// flush on graph-id change via atomicAdd (batch sorted => few flushes).
#define POOL_CHUNK 256
__global__ __launch_bounds__(256) void pool2(const float* __restrict__ feat,
                                             const int* __restrict__ batch,
                                             float* __restrict__ out, int n) {
    int wave = threadIdx.x >> 6;
    int lane = threadIdx.x & 63;
    int base = blockIdx.x * POOL_CHUNK;
    int end = base + POOL_CHUNK;
    if (end > n) end = n;
    const float2* f2 = (const float2*)feat;
    float accx = 0.f, accy = 0.f;
    int cur_g = -1;
    for (int i = base + wave; i < end; i += 4) {
        int g = batch[i];
        if (g != cur_g) {
            if (cur_g >= 0) {
                atomicAdd(&out[cur_g * 128 + lane * 2 + 0], accx);
                atomicAdd(&out[cur_g * 128 + lane * 2 + 1], accy);
            }
            cur_g = g;
            accx = 0.f; accy = 0.f;
        }
        float2 v = f2[(size_t)i * 64 + lane];
        accx += v.x;
        accy += v.y;
    }
    if (cur_g >= 0) {
        atomicAdd(&out[cur_g * 128 + lane * 2 + 0], accx);
        atomicAdd(&out[cur_g * 128 + lane * 2 + 1], accy);
    }
}

extern "C" void kernel_launch(void* const* d_in, const int* in_sizes, int n_in,
                              void* d_out, int out_size, void* d_ws, size_t ws_size,
                              hipStream_t stream) {
    const float* x  = (const float*)d_in[0];
    const int*   ei = (const int*)d_in[1];
    const int*   batch = (const int*)d_in[2];
    const float* W1 = (const float*)d_in[3];
    const float* b1 = (const float*)d_in[4];
    const float* W2 = (const float*)d_in[5];
    const float* b2 = (const float*)d_in[6];
    float* out = (float*)d_out;

    const int N = in_sizes[2];       // 50000
    const int E = in_sizes[1] / 2;   // 800000

    // workspace layout
    float* h  = (float*)d_ws;                       // N*128
    float* o  = h + (size_t)N * 128;                // N*128
    int* cnt  = (int*)(o + (size_t)N * 128);        // N
    int* row_start = cnt + N;                       // N
    int* cursor    = row_start + N;                 // N
    float* dinv    = (float*)(cursor + N);          // N
    int* src_sorted = (int*)(dinv + N);             // E
    float* enorm    = (float*)(src_sorted + E);     // E
    int* bsum       = (int*)(enorm + E);            // small

    const int nb = (N + 1023) / 1024;

    hipMemsetAsync(cnt, 0, (size_t)N * sizeof(int), stream);
    hipMemsetAsync(out, 0, (size_t)out_size * sizeof(float), stream);
    deg_count<<<(E + 255) / 256, 256, 0, stream>>>(ei, cnt, E);
    block_sums<<<nb, 256, 0, stream>>>(cnt, bsum, N);
    scan_bsum<<<1, 64, 0, stream>>>(bsum, nb);
    scan_final<<<nb, 256, 0, stream>>>(cnt, bsum, row_start, cursor, dinv, N);
    fill_edges<<<(E + 255) / 256, 256, 0, stream>>>(ei, cursor, dinv, src_sorted, enorm, E);

    const int gemm_grid = (N + 127) / 128;
    const int agg_grid = (N + 3) / 4;

    // layer 1
    gemm_xw<<<gemm_grid, 256, 0, stream>>>(x, W1, h, N);
    agg<true><<<agg_grid, 256, 0, stream>>>(h, src_sorted, enorm, row_start, cnt, dinv, b1, o, N);
    // layer 2
    gemm_xw<<<gemm_grid, 256, 0, stream>>>(o, W2, h, N);
    agg<false><<<agg_grid, 256, 0, stream>>>(h, src_sorted, enorm, row_start, cnt, dinv, b2, o, N);
    // pool
    pool2<<<(N + POOL_CHUNK - 1) / POOL_CHUNK, 256, 0, stream>>>(o, batch, out, N);
}

// Round 3
// 317.998 us; speedup vs baseline: 1.7140x; 1.2301x over previous
//
#include <hip/hip_runtime.h>
#include <hip/hip_bf16.h>

// GCN 2-layer + global_add_pool on MI355X.
// R2 changes:
//  - h/o stored as fp16: gather row 512B -> 256B (agg FETCH was 190MB/dispatch)
//  - GEMMs use mfma_f32_16x16x32_f16 (A staged+converted through LDS, W
//    pre-swizzled to fragment order by wprep)
//  - pool fused into agg2 (register pool acc + atomic flush on graph change)
//  - (src, norm) packed as int2: one 8B load per edge for index stream

typedef _Float16 f16x8 __attribute__((ext_vector_type(8)));
typedef float f32x4 __attribute__((ext_vector_type(4)));

static __device__ __forceinline__ float f16lo(unsigned int u) {
    union { unsigned short s; _Float16 h; } c; c.s = (unsigned short)(u & 0xffff);
    return (float)c.h;
}
static __device__ __forceinline__ float f16hi(unsigned int u) {
    union { unsigned short s; _Float16 h; } c; c.s = (unsigned short)(u >> 16);
    return (float)c.h;
}
static __device__ __forceinline__ unsigned int pack2f16(float x, float y) {
    union { unsigned short s; _Float16 h; } a, b;
    a.h = (_Float16)x; b.h = (_Float16)y;
    return (unsigned int)a.s | ((unsigned int)b.s << 16);
}

// ---------------- CSR build ----------------

__global__ void deg_count(const int* __restrict__ ei, int* __restrict__ cnt, int E) {
    int e = blockIdx.x * 256 + threadIdx.x;
    if (e < E) atomicAdd(&cnt[ei[E + e]], 1);  // ei[1][e] = dst
}

__global__ void block_sums(const int* __restrict__ cnt, int* __restrict__ bsum, int n) {
    __shared__ int s[256];
    int base = blockIdx.x * 1024;
    int t = threadIdx.x;
    int v = 0;
#pragma unroll
    for (int i = 0; i < 4; i++) {
        int idx = base + t * 4 + i;
        if (idx < n) v += cnt[idx];
    }
    s[t] = v;
    __syncthreads();
    for (int off = 128; off > 0; off >>= 1) {
        if (t < off) s[t] += s[t + off];
        __syncthreads();
    }
    if (t == 0) bsum[blockIdx.x] = s[0];
}

__global__ void scan_bsum(int* __restrict__ bsum, int nb) {
    if (threadIdx.x == 0 && blockIdx.x == 0) {
        int run = 0;
        for (int i = 0; i < nb; i++) { int v = bsum[i]; bsum[i] = run; run += v; }
    }
}

__global__ void scan_final(const int* __restrict__ cnt, const int* __restrict__ bsum,
                           int* __restrict__ row_start, int* __restrict__ cursor,
                           float* __restrict__ dinv, int n) {
    __shared__ int s[256];
    int base = blockIdx.x * 1024;
    int t = threadIdx.x;
    int loc[4];
    int v = 0;
#pragma unroll
    for (int i = 0; i < 4; i++) {
        int idx = base + t * 4 + i;
        loc[i] = (idx < n) ? cnt[idx] : 0;
        v += loc[i];
    }
    s[t] = v;
    __syncthreads();
    for (int off = 1; off < 256; off *= 2) {
        int u = (t >= off) ? s[t - off] : 0;
        __syncthreads();
        s[t] += u;
        __syncthreads();
    }
    int excl = s[t] - v + bsum[blockIdx.x];
#pragma unroll
    for (int i = 0; i < 4; i++) {
        int idx = base + t * 4 + i;
        if (idx < n) {
            row_start[idx] = excl;
            cursor[idx] = excl;
            dinv[idx] = rsqrtf((float)loc[i] + 1.0f);
            excl += loc[i];
        }
    }
}

__global__ void fill_edges(const int* __restrict__ ei, int* __restrict__ cursor,
                           const float* __restrict__ dinv, int2* __restrict__ edges, int E) {
    int e = blockIdx.x * 256 + threadIdx.x;
    if (e >= E) return;
    int s = ei[e];
    int d = ei[E + e];
    int pos = atomicAdd(&cursor[d], 1);
    edges[pos] = make_int2(s, __float_as_int(dinv[s] * dinv[d]));
}

// ---------------- W fragment prep ----------------
// wfrag[((nb*4+kc)*64 + lane)*8 + j] = W[kc*32 + (lane>>4)*8 + j][nb*16 + (lane&15)]
__global__ void wprep(const float* __restrict__ W, _Float16* __restrict__ wfrag) {
    int idx = blockIdx.x * 256 + threadIdx.x;  // 2048 total
    if (idx >= 2048) return;
    int lane = idx & 63;
    int kc = (idx >> 6) & 3;
    int nb = idx >> 8;
    int col = nb * 16 + (lane & 15);
    int krow = kc * 32 + (lane >> 4) * 8;
#pragma unroll
    for (int j = 0; j < 8; j++)
        wfrag[idx * 8 + j] = (_Float16)W[(krow + j) * 128 + col];
}

// ---------------- GEMM: C[M x 128] = A[M x 128] @ W, fp16 MFMA ----------------
// Block: 128 rows, 256 threads (4 waves). Wave w: rows [w*32, w*32+32).
// LDS A: 128 x 136 halves (pad +8 to spread banks).
template <bool A_IS_F32>
__global__ __launch_bounds__(256) void gemm_mfma(const void* __restrict__ Av,
                                                 const _Float16* __restrict__ wfrag,
                                                 _Float16* __restrict__ C, int M) {
    __shared__ _Float16 As[128 * 136];
    int t = threadIdx.x;
    int row0 = blockIdx.x * 128;

    if (A_IS_F32) {
        const float4* A4 = (const float4*)Av;
#pragma unroll
        for (int it = 0; it < 16; it++) {
            int v = it * 256 + t;          // 4096 float4 = 128 rows x 32
            int row = v >> 5;
            int seg = v & 31;
            float4 val = make_float4(0.f, 0.f, 0.f, 0.f);
            if (row0 + row < M) val = A4[(size_t)(row0 + row) * 32 + seg];
            _Float16* p = &As[row * 136 + seg * 4];
            p[0] = (_Float16)val.x; p[1] = (_Float16)val.y;
            p[2] = (_Float16)val.z; p[3] = (_Float16)val.w;
        }
    } else {
        const uint4* A4 = (const uint4*)Av;  // 8 halves per load
#pragma unroll
        for (int it = 0; it < 8; it++) {
            int v = it * 256 + t;          // 2048 chunks = 128 rows x 16
            int row = v >> 4;
            int seg = v & 15;
            uint4 val = make_uint4(0, 0, 0, 0);
            if (row0 + row < M) val = A4[(size_t)(row0 + row) * 16 + seg];
            *((uint4*)&As[row * 136 + seg * 8]) = val;
        }
    }
    __syncthreads();

    int wv = t >> 6;
    int lane = t & 63;
    int lrow = lane & 15;
    int lq = lane >> 4;

    f32x4 acc[2][8];
#pragma unroll
    for (int i = 0; i < 2; i++)
#pragma unroll
        for (int j = 0; j < 8; j++) acc[i][j] = (f32x4){0.f, 0.f, 0.f, 0.f};

#pragma unroll
    for (int kc = 0; kc < 4; kc++) {
        int k0 = kc * 32;
        f16x8 a0 = *((const f16x8*)&As[(wv * 32 + lrow) * 136 + k0 + lq * 8]);
        f16x8 a1 = *((const f16x8*)&As[(wv * 32 + 16 + lrow) * 136 + k0 + lq * 8]);
#pragma unroll
        for (int nb = 0; nb < 8; nb++) {
            f16x8 b = ((const f16x8*)wfrag)[(nb * 4 + kc) * 64 + lane];
            acc[0][nb] = __builtin_amdgcn_mfma_f32_16x16x32_f16(a0, b, acc[0][nb], 0, 0, 0);
            acc[1][nb] = __builtin_amdgcn_mfma_f32_16x16x32_f16(a1, b, acc[1][nb], 0, 0, 0);
        }
    }

    // C/D layout: col = lane&15, row = (lane>>4)*4 + reg
#pragma unroll
    for (int ti = 0; ti < 2; ti++) {
#pragma unroll
        for (int r = 0; r < 4; r++) {
            int row = row0 + wv * 32 + ti * 16 + lq * 4 + r;
            if (row < M) {
#pragma unroll
                for (int nb = 0; nb < 8; nb++)
                    C[(size_t)row * 128 + nb * 16 + lrow] = (_Float16)acc[ti][nb][r];
            }
        }
    }
}

// ---------------- agg layer 1: o = relu(gather + dinv^2*h + b1), fp16 ----------------
__global__ __launch_bounds__(256) void agg1(const _Float16* __restrict__ hb,
                                            const int2* __restrict__ edges,
                                            const int* __restrict__ row_start,
                                            const int* __restrict__ cnt,
                                            const float* __restrict__ dinv,
                                            const float* __restrict__ bias,
                                            _Float16* __restrict__ ob, int n) {
    int node = blockIdx.x * 4 + (threadIdx.x >> 6);
    if (node >= n) return;
    int lane = threadIdx.x & 63;
    int s0 = row_start[node];
    int c = cnt[node];
    const unsigned int* h2 = (const unsigned int*)hb;
    float ax = 0.f, ay = 0.f, bx = 0.f, by = 0.f;
    int e = 0;
    for (; e + 4 <= c; e += 4) {
        int2 eA = edges[s0 + e + 0];
        int2 eB = edges[s0 + e + 1];
        int2 eC = edges[s0 + e + 2];
        int2 eD = edges[s0 + e + 3];
        unsigned int vA = h2[(size_t)eA.x * 64 + lane];
        unsigned int vB = h2[(size_t)eB.x * 64 + lane];
        unsigned int vC = h2[(size_t)eC.x * 64 + lane];
        unsigned int vD = h2[(size_t)eD.x * 64 + lane];
        float wA = __int_as_float(eA.y), wB = __int_as_float(eB.y);
        float wC = __int_as_float(eC.y), wD = __int_as_float(eD.y);
        ax = fmaf(wA, f16lo(vA), ax); ay = fmaf(wA, f16hi(vA), ay);
        bx = fmaf(wB, f16lo(vB), bx); by = fmaf(wB, f16hi(vB), by);
        ax = fmaf(wC, f16lo(vC), ax); ay = fmaf(wC, f16hi(vC), ay);
        bx = fmaf(wD, f16lo(vD), bx); by = fmaf(wD, f16hi(vD), by);
    }
    for (; e < c; e++) {
        int2 ev = edges[s0 + e];
        unsigned int v = h2[(size_t)ev.x * 64 + lane];
        float w = __int_as_float(ev.y);
        ax = fmaf(w, f16lo(v), ax); ay = fmaf(w, f16hi(v), ay);
    }
    ax += bx; ay += by;
    float di = dinv[node];
    float sw = di * di;
    unsigned int hs = h2[(size_t)node * 64 + lane];
    float2 bv = ((const float2*)bias)[lane];
    float ox = ax + sw * f16lo(hs) + bv.x;
    float oy = ay + sw * f16hi(hs) + bv.y;
    ox = fmaxf(ox, 0.f); oy = fmaxf(oy, 0.f);
    ((unsigned int*)ob)[(size_t)node * 64 + lane] = pack2f16(ox, oy);
}

// ---------------- agg layer 2 + fused global_add_pool ----------------
// Block handles 64 consecutive nodes; wave w processes base+w, base+w+4, ...
// Pool sums accumulated in registers, flushed on graph change (batch sorted).
#define A2C 64
__global__ __launch_bounds__(256) void agg2_pool(const _Float16* __restrict__ hb,
                                                 const int2* __restrict__ edges,
                                                 const int* __restrict__ row_start,
                                                 const int* __restrict__ cnt,
                                                 const float* __restrict__ dinv,
                                                 const float* __restrict__ bias,
                                                 const int* __restrict__ batch,
                                                 float* __restrict__ out, int n) {
    int wv = threadIdx.x >> 6;
    int lane = threadIdx.x & 63;
    int base = blockIdx.x * A2C;
    int end = base + A2C;
    if (end > n) end = n;
    const unsigned int* h2 = (const unsigned int*)hb;
    float2 bv = ((const float2*)bias)[lane];
    float px = 0.f, py = 0.f;
    int cur_g = -1;
    for (int node = base + wv; node < end; node += 4) {
        int s0 = row_start[node];
        int c = cnt[node];
        float ax = 0.f, ay = 0.f, bx = 0.f, by = 0.f;
        int e = 0;
        for (; e + 4 <= c; e += 4) {
            int2 eA = edges[s0 + e + 0];
            int2 eB = edges[s0 + e + 1];
            int2 eC = edges[s0 + e + 2];
            int2 eD = edges[s0 + e + 3];
            unsigned int vA = h2[(size_t)eA.x * 64 + lane];
            unsigned int vB = h2[(size_t)eB.x * 64 + lane];
            unsigned int vC = h2[(size_t)eC.x * 64 + lane];
            unsigned int vD = h2[(size_t)eD.x * 64 + lane];
            float wA = __int_as_float(eA.y), wB = __int_as_float(eB.y);
            float wC = __int_as_float(eC.y), wD = __int_as_float(eD.y);
            ax = fmaf(wA, f16lo(vA), ax); ay = fmaf(wA, f16hi(vA), ay);
            bx = fmaf(wB, f16lo(vB), bx); by = fmaf(wB, f16hi(vB), by);
            ax = fmaf(wC, f16lo(vC), ax); ay = fmaf(wC, f16hi(vC), ay);
            bx = fmaf(wD, f16lo(vD), bx); by = fmaf(wD, f16hi(vD), by);
        }
        for (; e < c; e++) {
            int2 ev = edges[s0 + e];
            unsigned int v = h2[(size_t)ev.x * 64 + lane];
            float w = __int_as_float(ev.y);
            ax = fmaf(w, f16lo(v), ax); ay = fmaf(w, f16hi(v), ay);
        }
        ax += bx; ay += by;
        float di = dinv[node];
        float sw = di * di;
        unsigned int hs = h2[(size_t)node * 64 + lane];
        float ox = ax + sw * f16lo(hs) + bv.x;
        float oy = ay + sw * f16hi(hs) + bv.y;
        int g = batch[node];
        if (g != cur_g) {
            if (cur_g >= 0) {
                atomicAdd(&out[cur_g * 128 + lane * 2 + 0], px);
                atomicAdd(&out[cur_g * 128 + lane * 2 + 1], py);
            }
            cur_g = g;
            px = 0.f; py = 0.f;
        }
        px += ox; py += oy;
    }
    if (cur_g >= 0) {
        atomicAdd(&out[cur_g * 128 + lane * 2 + 0], px);
        atomicAdd(&out[cur_g * 128 + lane * 2 + 1], py);
    }
}

extern "C" void kernel_launch(void* const* d_in, const int* in_sizes, int n_in,
                              void* d_out, int out_size, void* d_ws, size_t ws_size,
                              hipStream_t stream) {
    const float* x  = (const float*)d_in[0];
    const int*   ei = (const int*)d_in[1];
    const int*   batch = (const int*)d_in[2];
    const float* W1 = (const float*)d_in[3];
    const float* b1 = (const float*)d_in[4];
    const float* W2 = (const float*)d_in[5];
    const float* b2 = (const float*)d_in[6];
    float* out = (float*)d_out;

    const int N = in_sizes[2];       // 50000
    const int E = in_sizes[1] / 2;   // 800000

    // workspace layout
    _Float16* hb = (_Float16*)d_ws;                  // N*128 halves
    _Float16* ob = hb + (size_t)N * 128;             // N*128 halves
    int* cnt  = (int*)(ob + (size_t)N * 128);        // N
    int* row_start = cnt + N;                        // N
    int* cursor    = row_start + N;                  // N
    float* dinv    = (float*)(cursor + N);           // N
    int2* edges    = (int2*)(dinv + N);              // E
    _Float16* wfrag1 = (_Float16*)(edges + E);       // 128*128
    _Float16* wfrag2 = wfrag1 + 128 * 128;           // 128*128
    int* bsum      = (int*)(wfrag2 + 128 * 128);     // small

    const int nb = (N + 1023) / 1024;

    hipMemsetAsync(cnt, 0, (size_t)N * sizeof(int), stream);
    hipMemsetAsync(out, 0, (size_t)out_size * sizeof(float), stream);
    wprep<<<8, 256, 0, stream>>>(W1, wfrag1);
    wprep<<<8, 256, 0, stream>>>(W2, wfrag2);
    deg_count<<<(E + 255) / 256, 256, 0, stream>>>(ei, cnt, E);
    block_sums<<<nb, 256, 0, stream>>>(cnt, bsum, N);
    scan_bsum<<<1, 64, 0, stream>>>(bsum, nb);
    scan_final<<<nb, 256, 0, stream>>>(cnt, bsum, row_start, cursor, dinv, N);
    fill_edges<<<(E + 255) / 256, 256, 0, stream>>>(ei, cursor, dinv, edges, E);

    const int gemm_grid = (N + 127) / 128;

    // layer 1
    gemm_mfma<true><<<gemm_grid, 256, 0, stream>>>(x, wfrag1, hb, N);
    agg1<<<(N + 3) / 4, 256, 0, stream>>>(hb, edges, row_start, cnt, dinv, b1, ob, N);
    // layer 2
    gemm_mfma<false><<<gemm_grid, 256, 0, stream>>>(ob, wfrag2, hb, N);
    // layer 2 aggregation + pool fused
    agg2_pool<<<(N + A2C - 1) / A2C, 256, 0, stream>>>(hb, edges, row_start, cnt, dinv, b2,
                                                       batch, out, N);
}

// Round 4
// 291.356 us; speedup vs baseline: 1.8708x; 1.0914x over previous
//
#include <hip/hip_runtime.h>
#include <hip/hip_bf16.h>

// GCN 2-layer + global_add_pool on MI355X.
// R3 changes:
//  - UN-fuse agg2+pool: A2C=64 fusion dropped to 3128 waves / 27% occupancy
//    and regressed (72.6us vs 60.9 f32). agg2 back to one-wave-per-node
//    (50000 waves), separate fp16 pool kernel (12.8MB read, registers+atomic
//    flush on graph boundary).
//  - agg gather loop unrolled x8 (8 independent edge->row load chains).

typedef _Float16 f16x8 __attribute__((ext_vector_type(8)));
typedef float f32x4 __attribute__((ext_vector_type(4)));

static __device__ __forceinline__ float f16lo(unsigned int u) {
    union { unsigned short s; _Float16 h; } c; c.s = (unsigned short)(u & 0xffff);
    return (float)c.h;
}
static __device__ __forceinline__ float f16hi(unsigned int u) {
    union { unsigned short s; _Float16 h; } c; c.s = (unsigned short)(u >> 16);
    return (float)c.h;
}
static __device__ __forceinline__ unsigned int pack2f16(float x, float y) {
    union { unsigned short s; _Float16 h; } a, b;
    a.h = (_Float16)x; b.h = (_Float16)y;
    return (unsigned int)a.s | ((unsigned int)b.s << 16);
}

// ---------------- CSR build ----------------

__global__ void deg_count(const int* __restrict__ ei, int* __restrict__ cnt, int E) {
    int e = blockIdx.x * 256 + threadIdx.x;
    if (e < E) atomicAdd(&cnt[ei[E + e]], 1);  // ei[1][e] = dst
}

__global__ void block_sums(const int* __restrict__ cnt, int* __restrict__ bsum, int n) {
    __shared__ int s[256];
    int base = blockIdx.x * 1024;
    int t = threadIdx.x;
    int v = 0;
#pragma unroll
    for (int i = 0; i < 4; i++) {
        int idx = base + t * 4 + i;
        if (idx < n) v += cnt[idx];
    }
    s[t] = v;
    __syncthreads();
    for (int off = 128; off > 0; off >>= 1) {
        if (t < off) s[t] += s[t + off];
        __syncthreads();
    }
    if (t == 0) bsum[blockIdx.x] = s[0];
}

__global__ void scan_bsum(int* __restrict__ bsum, int nb) {
    if (threadIdx.x == 0 && blockIdx.x == 0) {
        int run = 0;
        for (int i = 0; i < nb; i++) { int v = bsum[i]; bsum[i] = run; run += v; }
    }
}

__global__ void scan_final(const int* __restrict__ cnt, const int* __restrict__ bsum,
                           int* __restrict__ row_start, int* __restrict__ cursor,
                           float* __restrict__ dinv, int n) {
    __shared__ int s[256];
    int base = blockIdx.x * 1024;
    int t = threadIdx.x;
    int loc[4];
    int v = 0;
#pragma unroll
    for (int i = 0; i < 4; i++) {
        int idx = base + t * 4 + i;
        loc[i] = (idx < n) ? cnt[idx] : 0;
        v += loc[i];
    }
    s[t] = v;
    __syncthreads();
    for (int off = 1; off < 256; off *= 2) {
        int u = (t >= off) ? s[t - off] : 0;
        __syncthreads();
        s[t] += u;
        __syncthreads();
    }
    int excl = s[t] - v + bsum[blockIdx.x];
#pragma unroll
    for (int i = 0; i < 4; i++) {
        int idx = base + t * 4 + i;
        if (idx < n) {
            row_start[idx] = excl;
            cursor[idx] = excl;
            dinv[idx] = rsqrtf((float)loc[i] + 1.0f);
            excl += loc[i];
        }
    }
}

__global__ void fill_edges(const int* __restrict__ ei, int* __restrict__ cursor,
                           const float* __restrict__ dinv, int2* __restrict__ edges, int E) {
    int e = blockIdx.x * 256 + threadIdx.x;
    if (e >= E) return;
    int s = ei[e];
    int d = ei[E + e];
    int pos = atomicAdd(&cursor[d], 1);
    edges[pos] = make_int2(s, __float_as_int(dinv[s] * dinv[d]));
}

// ---------------- W fragment prep ----------------
__global__ void wprep(const float* __restrict__ W, _Float16* __restrict__ wfrag) {
    int idx = blockIdx.x * 256 + threadIdx.x;  // 2048 total
    if (idx >= 2048) return;
    int lane = idx & 63;
    int kc = (idx >> 6) & 3;
    int nb = idx >> 8;
    int col = nb * 16 + (lane & 15);
    int krow = kc * 32 + (lane >> 4) * 8;
#pragma unroll
    for (int j = 0; j < 8; j++)
        wfrag[idx * 8 + j] = (_Float16)W[(krow + j) * 128 + col];
}

// ---------------- GEMM: C[M x 128] = A[M x 128] @ W, fp16 MFMA ----------------
template <bool A_IS_F32>
__global__ __launch_bounds__(256) void gemm_mfma(const void* __restrict__ Av,
                                                 const _Float16* __restrict__ wfrag,
                                                 _Float16* __restrict__ C, int M) {
    __shared__ _Float16 As[128 * 136];
    int t = threadIdx.x;
    int row0 = blockIdx.x * 128;

    if (A_IS_F32) {
        const float4* A4 = (const float4*)Av;
#pragma unroll
        for (int it = 0; it < 16; it++) {
            int v = it * 256 + t;
            int row = v >> 5;
            int seg = v & 31;
            float4 val = make_float4(0.f, 0.f, 0.f, 0.f);
            if (row0 + row < M) val = A4[(size_t)(row0 + row) * 32 + seg];
            _Float16* p = &As[row * 136 + seg * 4];
            p[0] = (_Float16)val.x; p[1] = (_Float16)val.y;
            p[2] = (_Float16)val.z; p[3] = (_Float16)val.w;
        }
    } else {
        const uint4* A4 = (const uint4*)Av;
#pragma unroll
        for (int it = 0; it < 8; it++) {
            int v = it * 256 + t;
            int row = v >> 4;
            int seg = v & 15;
            uint4 val = make_uint4(0, 0, 0, 0);
            if (row0 + row < M) val = A4[(size_t)(row0 + row) * 16 + seg];
            *((uint4*)&As[row * 136 + seg * 8]) = val;
        }
    }
    __syncthreads();

    int wv = t >> 6;
    int lane = t & 63;
    int lrow = lane & 15;
    int lq = lane >> 4;

    f32x4 acc[2][8];
#pragma unroll
    for (int i = 0; i < 2; i++)
#pragma unroll
        for (int j = 0; j < 8; j++) acc[i][j] = (f32x4){0.f, 0.f, 0.f, 0.f};

#pragma unroll
    for (int kc = 0; kc < 4; kc++) {
        int k0 = kc * 32;
        f16x8 a0 = *((const f16x8*)&As[(wv * 32 + lrow) * 136 + k0 + lq * 8]);
        f16x8 a1 = *((const f16x8*)&As[(wv * 32 + 16 + lrow) * 136 + k0 + lq * 8]);
#pragma unroll
        for (int nb = 0; nb < 8; nb++) {
            f16x8 b = ((const f16x8*)wfrag)[(nb * 4 + kc) * 64 + lane];
            acc[0][nb] = __builtin_amdgcn_mfma_f32_16x16x32_f16(a0, b, acc[0][nb], 0, 0, 0);
            acc[1][nb] = __builtin_amdgcn_mfma_f32_16x16x32_f16(a1, b, acc[1][nb], 0, 0, 0);
        }
    }

    // C/D layout: col = lane&15, row = (lane>>4)*4 + reg
#pragma unroll
    for (int ti = 0; ti < 2; ti++) {
#pragma unroll
        for (int r = 0; r < 4; r++) {
            int row = row0 + wv * 32 + ti * 16 + lq * 4 + r;
            if (row < M) {
#pragma unroll
                for (int nb = 0; nb < 8; nb++)
                    C[(size_t)row * 128 + nb * 16 + lrow] = (_Float16)acc[ti][nb][r];
            }
        }
    }
}

// ---------------- agg: one wave per node, fp16 table, unroll x8 ----------------
template <bool RELU>
__global__ __launch_bounds__(256) void agg(const _Float16* __restrict__ hb,
                                           const int2* __restrict__ edges,
                                           const int* __restrict__ row_start,
                                           const int* __restrict__ cnt,
                                           const float* __restrict__ dinv,
                                           const float* __restrict__ bias,
                                           _Float16* __restrict__ ob, int n) {
    int node = blockIdx.x * 4 + (threadIdx.x >> 6);
    if (node >= n) return;
    int lane = threadIdx.x & 63;
    int s0 = row_start[node];
    int c = cnt[node];
    const unsigned int* h2 = (const unsigned int*)hb;
    float ax = 0.f, ay = 0.f, bx = 0.f, by = 0.f;
    int e = 0;
    for (; e + 8 <= c; e += 8) {
        int2 e0 = edges[s0 + e + 0];
        int2 e1 = edges[s0 + e + 1];
        int2 e2 = edges[s0 + e + 2];
        int2 e3 = edges[s0 + e + 3];
        int2 e4 = edges[s0 + e + 4];
        int2 e5 = edges[s0 + e + 5];
        int2 e6 = edges[s0 + e + 6];
        int2 e7 = edges[s0 + e + 7];
        unsigned int v0 = h2[(size_t)e0.x * 64 + lane];
        unsigned int v1 = h2[(size_t)e1.x * 64 + lane];
        unsigned int v2 = h2[(size_t)e2.x * 64 + lane];
        unsigned int v3 = h2[(size_t)e3.x * 64 + lane];
        unsigned int v4 = h2[(size_t)e4.x * 64 + lane];
        unsigned int v5 = h2[(size_t)e5.x * 64 + lane];
        unsigned int v6 = h2[(size_t)e6.x * 64 + lane];
        unsigned int v7 = h2[(size_t)e7.x * 64 + lane];
        float w0 = __int_as_float(e0.y), w1 = __int_as_float(e1.y);
        float w2 = __int_as_float(e2.y), w3 = __int_as_float(e3.y);
        float w4 = __int_as_float(e4.y), w5 = __int_as_float(e5.y);
        float w6 = __int_as_float(e6.y), w7 = __int_as_float(e7.y);
        ax = fmaf(w0, f16lo(v0), ax); ay = fmaf(w0, f16hi(v0), ay);
        bx = fmaf(w1, f16lo(v1), bx); by = fmaf(w1, f16hi(v1), by);
        ax = fmaf(w2, f16lo(v2), ax); ay = fmaf(w2, f16hi(v2), ay);
        bx = fmaf(w3, f16lo(v3), bx); by = fmaf(w3, f16hi(v3), by);
        ax = fmaf(w4, f16lo(v4), ax); ay = fmaf(w4, f16hi(v4), ay);
        bx = fmaf(w5, f16lo(v5), bx); by = fmaf(w5, f16hi(v5), by);
        ax = fmaf(w6, f16lo(v6), ax); ay = fmaf(w6, f16hi(v6), ay);
        bx = fmaf(w7, f16lo(v7), bx); by = fmaf(w7, f16hi(v7), by);
    }
    for (; e + 4 <= c; e += 4) {
        int2 e0 = edges[s0 + e + 0];
        int2 e1 = edges[s0 + e + 1];
        int2 e2 = edges[s0 + e + 2];
        int2 e3 = edges[s0 + e + 3];
        unsigned int v0 = h2[(size_t)e0.x * 64 + lane];
        unsigned int v1 = h2[(size_t)e1.x * 64 + lane];
        unsigned int v2 = h2[(size_t)e2.x * 64 + lane];
        unsigned int v3 = h2[(size_t)e3.x * 64 + lane];
        float w0 = __int_as_float(e0.y), w1 = __int_as_float(e1.y);
        float w2 = __int_as_float(e2.y), w3 = __int_as_float(e3.y);
        ax = fmaf(w0, f16lo(v0), ax); ay = fmaf(w0, f16hi(v0), ay);
        bx = fmaf(w1, f16lo(v1), bx); by = fmaf(w1, f16hi(v1), by);
        ax = fmaf(w2, f16lo(v2), ax); ay = fmaf(w2, f16hi(v2), ay);
        bx = fmaf(w3, f16lo(v3), bx); by = fmaf(w3, f16hi(v3), by);
    }
    for (; e < c; e++) {
        int2 ev = edges[s0 + e];
        unsigned int v = h2[(size_t)ev.x * 64 + lane];
        float w = __int_as_float(ev.y);
        ax = fmaf(w, f16lo(v), ax); ay = fmaf(w, f16hi(v), ay);
    }
    ax += bx; ay += by;
    float di = dinv[node];
    float sw = di * di;
    unsigned int hs = h2[(size_t)node * 64 + lane];
    float2 bv = ((const float2*)bias)[lane];
    float ox = ax + sw * f16lo(hs) + bv.x;
    float oy = ay + sw * f16hi(hs) + bv.y;
    if (RELU) { ox = fmaxf(ox, 0.f); oy = fmaxf(oy, 0.f); }
    ((unsigned int*)ob)[(size_t)node * 64 + lane] = pack2f16(ox, oy);
}

// ---------------- global_add_pool over fp16 features ----------------
#define POOL_CHUNK 128
__global__ __launch_bounds__(256) void pool2h(const _Float16* __restrict__ feat,
                                              const int* __restrict__ batch,
                                              float* __restrict__ out, int n) {
    int wave = threadIdx.x >> 6;
    int lane = threadIdx.x & 63;
    int base = blockIdx.x * POOL_CHUNK;
    int end = base + POOL_CHUNK;
    if (end > n) end = n;
    const unsigned int* f2 = (const unsigned int*)feat;
    float accx = 0.f, accy = 0.f;
    int cur_g = -1;
    for (int i = base + wave; i < end; i += 4) {
        int g = batch[i];
        if (g != cur_g) {
            if (cur_g >= 0) {
                atomicAdd(&out[cur_g * 128 + lane * 2 + 0], accx);
                atomicAdd(&out[cur_g * 128 + lane * 2 + 1], accy);
            }
            cur_g = g;
            accx = 0.f; accy = 0.f;
        }
        unsigned int v = f2[(size_t)i * 64 + lane];
        accx += f16lo(v);
        accy += f16hi(v);
    }
    if (cur_g >= 0) {
        atomicAdd(&out[cur_g * 128 + lane * 2 + 0], accx);
        atomicAdd(&out[cur_g * 128 + lane * 2 + 1], accy);
    }
}

extern "C" void kernel_launch(void* const* d_in, const int* in_sizes, int n_in,
                              void* d_out, int out_size, void* d_ws, size_t ws_size,
                              hipStream_t stream) {
    const float* x  = (const float*)d_in[0];
    const int*   ei = (const int*)d_in[1];
    const int*   batch = (const int*)d_in[2];
    const float* W1 = (const float*)d_in[3];
    const float* b1 = (const float*)d_in[4];
    const float* W2 = (const float*)d_in[5];
    const float* b2 = (const float*)d_in[6];
    float* out = (float*)d_out;

    const int N = in_sizes[2];       // 50000
    const int E = in_sizes[1] / 2;   // 800000

    // workspace layout
    _Float16* hb = (_Float16*)d_ws;                  // N*128 halves
    _Float16* ob = hb + (size_t)N * 128;             // N*128 halves
    int* cnt  = (int*)(ob + (size_t)N * 128);        // N
    int* row_start = cnt + N;                        // N
    int* cursor    = row_start + N;                  // N
    float* dinv    = (float*)(cursor + N);           // N
    int2* edges    = (int2*)(dinv + N);              // E
    _Float16* wfrag1 = (_Float16*)(edges + E);       // 128*128
    _Float16* wfrag2 = wfrag1 + 128 * 128;           // 128*128
    int* bsum      = (int*)(wfrag2 + 128 * 128);     // small

    const int nb = (N + 1023) / 1024;

    hipMemsetAsync(cnt, 0, (size_t)N * sizeof(int), stream);
    hipMemsetAsync(out, 0, (size_t)out_size * sizeof(float), stream);
    wprep<<<8, 256, 0, stream>>>(W1, wfrag1);
    wprep<<<8, 256, 0, stream>>>(W2, wfrag2);
    deg_count<<<(E + 255) / 256, 256, 0, stream>>>(ei, cnt, E);
    block_sums<<<nb, 256, 0, stream>>>(cnt, bsum, N);
    scan_bsum<<<1, 64, 0, stream>>>(bsum, nb);
    scan_final<<<nb, 256, 0, stream>>>(cnt, bsum, row_start, cursor, dinv, N);
    fill_edges<<<(E + 255) / 256, 256, 0, stream>>>(ei, cursor, dinv, edges, E);

    const int gemm_grid = (N + 127) / 128;

    // layer 1
    gemm_mfma<true><<<gemm_grid, 256, 0, stream>>>(x, wfrag1, hb, N);
    agg<true><<<(N + 3) / 4, 256, 0, stream>>>(hb, edges, row_start, cnt, dinv, b1, ob, N);
    // layer 2
    gemm_mfma<false><<<gemm_grid, 256, 0, stream>>>(ob, wfrag2, hb, N);
    agg<false><<<(N + 3) / 4, 256, 0, stream>>>(hb, edges, row_start, cnt, dinv, b2, ob, N);
    // pool
    pool2h<<<(N + POOL_CHUNK - 1) / POOL_CHUNK, 256, 0, stream>>>(ob, batch, out, N);
}